// Round 1
// baseline (2400.235 us; speedup 1.0000x reference)
//
#include <hip/hip_runtime.h>
#include <hip/hip_bf16.h>
#include <math.h>

constexpr int KN  = 100;            // K (multi_factor * top_k)
constexpr int DE  = 64;             // embedding dim
constexpr int CAT = 2 * KN * DE;    // 12800
constexpr int HID = 128;

// ---------------------------------------------------------------------------
// Kernel 1: per-batch-row gather + einsum  scored = S(100x100) @ E(100x64)
// One block per batch row. 256 threads = (16 kt) x (16 dt).
// Thread computes k = kt*7+i (i<7, clamped), d = dt*4..dt*4+3.
// E staged in LDS (26KB); S rows read directly from global (broadcast float4).
// ---------------------------------------------------------------------------
__global__ __launch_bounds__(256) void einsum_kernel(
    const int* __restrict__ u_idx, const int* __restrict__ i_idx,
    const int* __restrict__ u_nbt, const int* __restrict__ i_nbt,
    const float* __restrict__ u_scr, const float* __restrict__ i_scr,
    const float* __restrict__ u_emb, const float* __restrict__ i_emb,
    float* __restrict__ x, int b0)
{
    __shared__ int   nb[KN];
    __shared__ float E[KN][DE];     // 25.6 KB

    const int t  = threadIdx.x;
    const int dt = t & 15;
    const int kt = t >> 4;
    const int b  = b0 + blockIdx.x;
    float* xr_base = x + (size_t)blockIdx.x * CAT;

    for (int side = 0; side < 2; ++side) {
        const int*   idxs = side ? i_idx : u_idx;
        const int*   nbt  = side ? i_nbt : u_nbt;
        const float* scr  = side ? i_scr : u_scr;
        const float* emb  = side ? i_emb : u_emb;

        if (side) __syncthreads();               // LDS reuse barrier

        const int center = idxs[b];
        if (t < KN) nb[t] = nbt[(size_t)center * KN + t];
        __syncthreads();

        // stage E[j][d] = emb[nb[j]][d]  (float4 loads, coalesced per row)
        for (int f = t; f < KN * (DE / 4); f += 256) {
            int j = f >> 4, d4 = f & 15;
            *(float4*)&E[j][d4 * 4] =
                *(const float4*)&emb[(size_t)nb[j] * DE + d4 * 4];
        }
        __syncthreads();

        // per-thread S row pointers (k clamped; garbage rows never written)
        const float* srow[7];
        #pragma unroll
        for (int i = 0; i < 7; ++i) {
            int k = kt * 7 + i;
            if (k > KN - 1) k = KN - 1;
            srow[i] = scr + (size_t)nb[k] * KN;
        }

        float4 acc[7];
        #pragma unroll
        for (int i = 0; i < 7; ++i) acc[i] = make_float4(0.f, 0.f, 0.f, 0.f);

        for (int j0 = 0; j0 < KN; j0 += 4) {
            float4 e0 = *(const float4*)&E[j0 + 0][dt * 4];
            float4 e1 = *(const float4*)&E[j0 + 1][dt * 4];
            float4 e2 = *(const float4*)&E[j0 + 2][dt * 4];
            float4 e3 = *(const float4*)&E[j0 + 3][dt * 4];
            #pragma unroll
            for (int i = 0; i < 7; ++i) {
                float4 s = *(const float4*)(srow[i] + j0);
                acc[i].x = fmaf(s.w, e3.x, fmaf(s.z, e2.x, fmaf(s.y, e1.x, fmaf(s.x, e0.x, acc[i].x))));
                acc[i].y = fmaf(s.w, e3.y, fmaf(s.z, e2.y, fmaf(s.y, e1.y, fmaf(s.x, e0.y, acc[i].y))));
                acc[i].z = fmaf(s.w, e3.z, fmaf(s.z, e2.z, fmaf(s.y, e1.z, fmaf(s.x, e0.z, acc[i].z))));
                acc[i].w = fmaf(s.w, e3.w, fmaf(s.z, e2.w, fmaf(s.y, e1.w, fmaf(s.x, e0.w, acc[i].w))));
            }
        }

        float* xr = xr_base + side * (KN * DE);
        #pragma unroll
        for (int i = 0; i < 7; ++i) {
            int k = kt * 7 + i;
            if (k < KN) *(float4*)&xr[k * DE + dt * 4] = acc[i];
        }
    }
}

// ---------------------------------------------------------------------------
// Kernel 2: h = relu(x @ W1 + b1); o = relu(h @ W2 + b2); out = sigmoid(o)
// Block tile: 32 rows x 128 cols. 256 threads = (8 rt) x (32 ct).
// Thread computes 4 rows x 4 cols. W1 tile (64x128) staged in LDS;
// x rows read from global (wave-broadcast b128, each chunk read once).
// Fused epilogue: shfl_xor reduce over the 32 ct lanes -> sigmoid -> out.
// ---------------------------------------------------------------------------
__global__ __launch_bounds__(256) void mlp_kernel(
    const float* __restrict__ x, const float* __restrict__ W1,
    const float* __restrict__ b1, const float* __restrict__ W2,
    const float* __restrict__ b2, float* __restrict__ out, int b0)
{
    __shared__ float Wt[64][HID];   // 32 KB

    const int t  = threadIdx.x;
    const int ct = t & 31;
    const int rt = t >> 5;
    const int row0 = blockIdx.x * 32;
    const float* xA = x + (size_t)row0 * CAT;

    float4 c[4];
    #pragma unroll
    for (int i = 0; i < 4; ++i) c[i] = make_float4(0.f, 0.f, 0.f, 0.f);

    for (int k0 = 0; k0 < CAT; k0 += 64) {
        if (k0) __syncthreads();
        // stage W1[k0..k0+63][0..127]
        for (int f = t; f < 64 * (HID / 4); f += 256) {
            int kk = f >> 5, n4 = f & 31;
            *(float4*)&Wt[kk][n4 * 4] =
                *(const float4*)&W1[(size_t)(k0 + kk) * HID + n4 * 4];
        }
        __syncthreads();

        #pragma unroll
        for (int kk4 = 0; kk4 < 16; ++kk4) {
            const int kk = kk4 * 4;
            float a[4][4];
            #pragma unroll
            for (int i = 0; i < 4; ++i) {
                float4 v = *(const float4*)&xA[(size_t)(rt * 4 + i) * CAT + k0 + kk];
                a[i][0] = v.x; a[i][1] = v.y; a[i][2] = v.z; a[i][3] = v.w;
            }
            #pragma unroll
            for (int q = 0; q < 4; ++q) {
                float4 w = *(const float4*)&Wt[kk + q][ct * 4];
                #pragma unroll
                for (int i = 0; i < 4; ++i) {
                    float av = a[i][q];
                    c[i].x = fmaf(av, w.x, c[i].x);
                    c[i].y = fmaf(av, w.y, c[i].y);
                    c[i].z = fmaf(av, w.z, c[i].z);
                    c[i].w = fmaf(av, w.w, c[i].w);
                }
            }
        }
    }

    // fused epilogue
    const float4 bb  = *(const float4*)&b1[ct * 4];
    const float4 w2v = *(const float4*)&W2[ct * 4];
    const float  b2v = b2[0];

    #pragma unroll
    for (int i = 0; i < 4; ++i) {
        float h0 = fmaxf(c[i].x + bb.x, 0.f);
        float h1 = fmaxf(c[i].y + bb.y, 0.f);
        float h2 = fmaxf(c[i].z + bb.z, 0.f);
        float h3 = fmaxf(c[i].w + bb.w, 0.f);
        float p = fmaf(h0, w2v.x, fmaf(h1, w2v.y, fmaf(h2, w2v.z, h3 * w2v.w)));
        #pragma unroll
        for (int m = 1; m < 32; m <<= 1) p += __shfl_xor(p, m, 64);
        if (ct == 0) {
            float o = fmaxf(p + b2v, 0.f);
            out[b0 + row0 + rt * 4 + i] = 1.f / (1.f + expf(-o));
        }
    }
}

// ---------------------------------------------------------------------------
extern "C" void kernel_launch(void* const* d_in, const int* in_sizes, int n_in,
                              void* d_out, int out_size, void* d_ws, size_t ws_size,
                              hipStream_t stream)
{
    const int*   user_idxs = (const int*)d_in[0];
    const int*   item_idxs = (const int*)d_in[1];
    const int*   user_nbt  = (const int*)d_in[2];
    const int*   item_nbt  = (const int*)d_in[3];
    const float* user_scr  = (const float*)d_in[4];
    const float* item_scr  = (const float*)d_in[5];
    const float* user_emb  = (const float*)d_in[6];
    const float* item_emb  = (const float*)d_in[7];
    const float* W1        = (const float*)d_in[8];
    const float* b1        = (const float*)d_in[9];
    const float* W2        = (const float*)d_in[10];
    const float* b2        = (const float*)d_in[11];
    float*       out       = (float*)d_out;

    const int B = in_sizes[0];      // 8192
    float* xbuf = (float*)d_ws;

    const size_t row_bytes = (size_t)CAT * sizeof(float);
    long max_rows = (long)(ws_size / row_bytes);
    int chunk = (int)((max_rows / 32) * 32);
    if (chunk > B) chunk = B;
    if (chunk < 32) chunk = 32;     // assume ws >= 1.6 MB

    for (int b0 = 0; b0 < B; b0 += chunk) {
        int rows = (B - b0 < chunk) ? (B - b0) : chunk;
        einsum_kernel<<<rows, 256, 0, stream>>>(
            user_idxs, item_idxs, user_nbt, item_nbt,
            user_scr, item_scr, user_emb, item_emb, xbuf, b0);
        mlp_kernel<<<rows / 32, 256, 0, stream>>>(
            xbuf, W1, b1, W2, b2, out, b0);
    }
}

// Round 2
// 547.345 us; speedup vs baseline: 4.3852x; 4.3852x over previous
//
#include <hip/hip_runtime.h>
#include <hip/hip_bf16.h>
#include <math.h>

constexpr int KN  = 100;            // K (multi_factor * top_k)
constexpr int DE  = 64;             // embedding dim
constexpr int CAT = 2 * KN * DE;    // 12800
constexpr int HID = 128;

typedef __bf16          bf16x8  __attribute__((ext_vector_type(8)));
typedef float           f32x4   __attribute__((ext_vector_type(4)));
typedef unsigned short  ushort8v __attribute__((ext_vector_type(8)));
typedef unsigned short  ushort4v __attribute__((ext_vector_type(4)));

static __device__ __forceinline__ unsigned short f2bf(float f) {
    __hip_bfloat16 h = __float2bfloat16(f);
    return *reinterpret_cast<unsigned short*>(&h);
}

// ---------------------------------------------------------------------------
// prep: w1t[n][k] = bf16(W1[k][n]); LDS-transposed so both sides coalesce.
// grid = CAT/64 = 200 blocks, 256 threads. k0 = blockIdx.x*64.
// ---------------------------------------------------------------------------
__global__ __launch_bounds__(256) void prep_w1t(
    const float* __restrict__ W1, unsigned short* __restrict__ w1t)
{
    __shared__ unsigned short T[HID][72];   // [n][kk], pad to 72
    const int t  = threadIdx.x;
    const int k0 = blockIdx.x * 64;

    for (int idx = t; idx < 64 * HID; idx += 256) {
        int kk = idx >> 7, n = idx & 127;          // consecutive t -> consecutive n
        T[n][kk] = f2bf(W1[(size_t)(k0 + kk) * HID + n]);
    }
    __syncthreads();
    for (int idx = t; idx < HID * 16; idx += 256) {
        int n = idx >> 4, c4 = idx & 15;
        *(ushort4v*)&w1t[(size_t)n * CAT + k0 + c4 * 4] =
            *(const ushort4v*)&T[n][c4 * 4];
    }
}

// ---------------------------------------------------------------------------
// Kernel 1: per (batch row, side) gather + einsum  scored = S(100x100)@E(100x64)
// grid = (rows, 2). 256 threads = (16 kt) x (16 dt); fp32 compute; bf16 out.
// ---------------------------------------------------------------------------
__global__ __launch_bounds__(256) void einsum_kernel(
    const int* __restrict__ u_idx, const int* __restrict__ i_idx,
    const int* __restrict__ u_nbt, const int* __restrict__ i_nbt,
    const float* __restrict__ u_scr, const float* __restrict__ i_scr,
    const float* __restrict__ u_emb, const float* __restrict__ i_emb,
    unsigned short* __restrict__ xb, int b0)
{
    __shared__ int   nb[KN];
    __shared__ float E[KN][DE];     // 25.6 KB

    const int t    = threadIdx.x;
    const int dt   = t & 15;
    const int kt   = t >> 4;
    const int side = blockIdx.y;
    const int b    = b0 + blockIdx.x;

    const int*   idxs = side ? i_idx : u_idx;
    const int*   nbt  = side ? i_nbt : u_nbt;
    const float* scr  = side ? i_scr : u_scr;
    const float* emb  = side ? i_emb : u_emb;

    const int center = idxs[b];
    if (t < KN) nb[t] = nbt[(size_t)center * KN + t];
    __syncthreads();

    for (int f = t; f < KN * (DE / 4); f += 256) {
        int j = f >> 4, d4 = f & 15;
        *(float4*)&E[j][d4 * 4] =
            *(const float4*)&emb[(size_t)nb[j] * DE + d4 * 4];
    }
    __syncthreads();

    const float* srow[7];
    #pragma unroll
    for (int i = 0; i < 7; ++i) {
        int k = kt * 7 + i;
        if (k > KN - 1) k = KN - 1;
        srow[i] = scr + (size_t)nb[k] * KN;
    }

    float4 acc[7];
    #pragma unroll
    for (int i = 0; i < 7; ++i) acc[i] = make_float4(0.f, 0.f, 0.f, 0.f);

    for (int j0 = 0; j0 < KN; j0 += 4) {
        float4 e0 = *(const float4*)&E[j0 + 0][dt * 4];
        float4 e1 = *(const float4*)&E[j0 + 1][dt * 4];
        float4 e2 = *(const float4*)&E[j0 + 2][dt * 4];
        float4 e3 = *(const float4*)&E[j0 + 3][dt * 4];
        #pragma unroll
        for (int i = 0; i < 7; ++i) {
            float4 s = *(const float4*)(srow[i] + j0);
            acc[i].x = fmaf(s.w, e3.x, fmaf(s.z, e2.x, fmaf(s.y, e1.x, fmaf(s.x, e0.x, acc[i].x))));
            acc[i].y = fmaf(s.w, e3.y, fmaf(s.z, e2.y, fmaf(s.y, e1.y, fmaf(s.x, e0.y, acc[i].y))));
            acc[i].z = fmaf(s.w, e3.z, fmaf(s.z, e2.z, fmaf(s.y, e1.z, fmaf(s.x, e0.z, acc[i].z))));
            acc[i].w = fmaf(s.w, e3.w, fmaf(s.z, e2.w, fmaf(s.y, e1.w, fmaf(s.x, e0.w, acc[i].w))));
        }
    }

    unsigned short* xr = xb + (size_t)blockIdx.x * CAT + side * (KN * DE);
    #pragma unroll
    for (int i = 0; i < 7; ++i) {
        int k = kt * 7 + i;
        if (k < KN) {
            ushort4v v = { f2bf(acc[i].x), f2bf(acc[i].y),
                           f2bf(acc[i].z), f2bf(acc[i].w) };
            *(ushort4v*)&xr[k * DE + dt * 4] = v;
        }
    }
}

// ---------------------------------------------------------------------------
// Kernel 2: bf16 MFMA MLP. BM=32 rows, BN=128 (all cols), BK=128, full K.
// 256 threads = 4 waves; wave w owns cols [w*32, w*32+32), all 32 rows.
// Fragments: 16x16x32 bf16; acc[2 Mt][2 Nt]. Fused bias/relu/W2/sigmoid.
// ---------------------------------------------------------------------------
__global__ __launch_bounds__(256) void mlp_kernel(
    const unsigned short* __restrict__ xb, const unsigned short* __restrict__ w1t,
    const float* __restrict__ b1, const float* __restrict__ W2,
    const float* __restrict__ b2, float* __restrict__ out, int b0)
{
    __shared__ unsigned short A[32][136];    // 8.7 KB  (pad +8 bf16 -> 2-way banks)
    __shared__ unsigned short Bt[HID][136];  // 34.8 KB
    __shared__ float red[4][32];

    const int t    = threadIdx.x;
    const int w    = t >> 6;
    const int l    = t & 63;
    const int cl   = l & 15;
    const int rgrp = l >> 4;
    const int row0 = blockIdx.x * 32;

    f32x4 acc[2][2];
    #pragma unroll
    for (int i = 0; i < 2; ++i)
        #pragma unroll
        for (int j = 0; j < 2; ++j)
            acc[i][j] = (f32x4){0.f, 0.f, 0.f, 0.f};

    for (int kb = 0; kb < CAT; kb += 128) {
        if (kb) __syncthreads();
        // stage A: 32 rows x 128 k  (512 16B-chunks, 2/thread)
        #pragma unroll
        for (int i = 0; i < 2; ++i) {
            int c = t + i * 256;
            int r = c >> 4, c16 = c & 15;
            *(ushort8v*)&A[r][c16 * 8] =
                *(const ushort8v*)&xb[(size_t)(row0 + r) * CAT + kb + c16 * 8];
        }
        // stage Bt: 128 n-rows x 128 k  (2048 chunks, 8/thread)
        #pragma unroll
        for (int i = 0; i < 8; ++i) {
            int c = t + i * 256;
            int n = c >> 4, c16 = c & 15;
            *(ushort8v*)&Bt[n][c16 * 8] =
                *(const ushort8v*)&w1t[(size_t)n * CAT + kb + c16 * 8];
        }
        __syncthreads();

        #pragma unroll
        for (int ks = 0; ks < 4; ++ks) {
            const int kcol = ks * 32 + rgrp * 8;
            bf16x8 a0 = *(const bf16x8*)&A[cl][kcol];
            bf16x8 a1 = *(const bf16x8*)&A[16 + cl][kcol];
            bf16x8 v0 = *(const bf16x8*)&Bt[w * 32 + cl][kcol];
            bf16x8 v1 = *(const bf16x8*)&Bt[w * 32 + 16 + cl][kcol];
            acc[0][0] = __builtin_amdgcn_mfma_f32_16x16x32_bf16(a0, v0, acc[0][0], 0, 0, 0);
            acc[0][1] = __builtin_amdgcn_mfma_f32_16x16x32_bf16(a0, v1, acc[0][1], 0, 0, 0);
            acc[1][0] = __builtin_amdgcn_mfma_f32_16x16x32_bf16(a1, v0, acc[1][0], 0, 0, 0);
            acc[1][1] = __builtin_amdgcn_mfma_f32_16x16x32_bf16(a1, v1, acc[1][1], 0, 0, 0);
        }
    }

    // fused epilogue: h = relu(acc + b1); p = h . W2; reduce 16 col-lanes,
    // then cross-wave via LDS; o = relu(p + b2); out = sigmoid(o).
    const float b1c0 = b1[w * 32 + cl];
    const float b1c1 = b1[w * 32 + 16 + cl];
    const float w2c0 = W2[w * 32 + cl];
    const float w2c1 = W2[w * 32 + 16 + cl];

    #pragma unroll
    for (int mt = 0; mt < 2; ++mt) {
        #pragma unroll
        for (int r = 0; r < 4; ++r) {
            float h0 = fmaxf(acc[mt][0][r] + b1c0, 0.f);
            float h1 = fmaxf(acc[mt][1][r] + b1c1, 0.f);
            float p  = fmaf(h0, w2c0, h1 * w2c1);
            p += __shfl_xor(p, 1, 64);
            p += __shfl_xor(p, 2, 64);
            p += __shfl_xor(p, 4, 64);
            p += __shfl_xor(p, 8, 64);
            if (cl == 0) red[w][mt * 16 + rgrp * 4 + r] = p;
        }
    }
    __syncthreads();
    if (t < 32) {
        float o = red[0][t] + red[1][t] + red[2][t] + red[3][t] + b2[0];
        o = fmaxf(o, 0.f);
        out[b0 + row0 + t] = 1.f / (1.f + expf(-o));
    }
}

// ---------------------------------------------------------------------------
extern "C" void kernel_launch(void* const* d_in, const int* in_sizes, int n_in,
                              void* d_out, int out_size, void* d_ws, size_t ws_size,
                              hipStream_t stream)
{
    const int*   user_idxs = (const int*)d_in[0];
    const int*   item_idxs = (const int*)d_in[1];
    const int*   user_nbt  = (const int*)d_in[2];
    const int*   item_nbt  = (const int*)d_in[3];
    const float* user_scr  = (const float*)d_in[4];
    const float* item_scr  = (const float*)d_in[5];
    const float* user_emb  = (const float*)d_in[6];
    const float* item_emb  = (const float*)d_in[7];
    const float* W1        = (const float*)d_in[8];
    const float* b1        = (const float*)d_in[9];
    const float* W2        = (const float*)d_in[10];
    const float* b2        = (const float*)d_in[11];
    float*       out       = (float*)d_out;

    const int B = in_sizes[0];      // 8192

    // ws layout: [w1t bf16: HID*CAT][xb bf16: chunk*CAT]
    const size_t w1t_bytes = (size_t)HID * CAT * sizeof(unsigned short); // 3.3 MB
    unsigned short* w1t = (unsigned short*)d_ws;
    unsigned short* xb  = (unsigned short*)((char*)d_ws + w1t_bytes);

    const size_t row_bytes = (size_t)CAT * sizeof(unsigned short);
    long max_rows = (long)((ws_size - w1t_bytes) / row_bytes);
    int chunk = (int)((max_rows / 32) * 32);
    if (chunk > B) chunk = B;
    if (chunk < 32) chunk = 32;     // ws is known >= 420 MB from round 1

    prep_w1t<<<CAT / 64, 256, 0, stream>>>(W1, w1t);

    for (int b0 = 0; b0 < B; b0 += chunk) {
        int rows = (B - b0 < chunk) ? (B - b0) : chunk;
        einsum_kernel<<<dim3(rows, 2), 256, 0, stream>>>(
            user_idxs, item_idxs, user_nbt, item_nbt,
            user_scr, item_scr, user_emb, item_emb, xb, b0);
        mlp_kernel<<<rows / 32, 256, 0, stream>>>(
            xb, w1t, b1, W2, b2, out, b0);
    }
}

// Round 3
// 368.912 us; speedup vs baseline: 6.5063x; 1.4837x over previous
//
#include <hip/hip_runtime.h>
#include <hip/hip_bf16.h>
#include <math.h>

constexpr int KN  = 100;            // K (multi_factor * top_k)
constexpr int DE  = 64;             // embedding dim
constexpr int CAT = 2 * KN * DE;    // 12800
constexpr int HID = 128;

typedef __bf16          bf16x8   __attribute__((ext_vector_type(8)));
typedef float           f32x4    __attribute__((ext_vector_type(4)));
typedef unsigned short  ushort8v __attribute__((ext_vector_type(8)));
typedef unsigned short  ushort4v __attribute__((ext_vector_type(4)));

static __device__ __forceinline__ unsigned short f2bf(float f) {
    __hip_bfloat16 h = __float2bfloat16(f);
    return *reinterpret_cast<unsigned short*>(&h);
}

// ---------------------------------------------------------------------------
// prep: w1t[n][k] = bf16(W1[k][n]); LDS-transposed so both sides coalesce.
// ---------------------------------------------------------------------------
__global__ __launch_bounds__(256) void prep_w1t(
    const float* __restrict__ W1, unsigned short* __restrict__ w1t)
{
    __shared__ unsigned short T[HID][72];
    const int t  = threadIdx.x;
    const int k0 = blockIdx.x * 64;

    for (int idx = t; idx < 64 * HID; idx += 256) {
        int kk = idx >> 7, n = idx & 127;
        T[n][kk] = f2bf(W1[(size_t)(k0 + kk) * HID + n]);
    }
    __syncthreads();
    for (int idx = t; idx < HID * 16; idx += 256) {
        int n = idx >> 4, c4 = idx & 15;
        *(ushort4v*)&w1t[(size_t)n * CAT + k0 + c4 * 4] =
            *(const ushort4v*)&T[n][c4 * 4];
    }
}

// ---------------------------------------------------------------------------
// Kernel 1 (MFMA): per (batch row, side) block computes scored = S @ E with
// 16x16x32 bf16 MFMA.  S[112][136] bf16 row-major (A-frag ready);
// Et[64][136] bf16 = E transposed (B-frag ready).  K padded 100->128 with
// zeroed strips on BOTH operands (NaN*0 hazard).  Output bounced through LDS
// (reusing S space) for coalesced bf16 stores to x.
// ---------------------------------------------------------------------------
__global__ __launch_bounds__(256) void einsum_mfma(
    const int* __restrict__ u_idx, const int* __restrict__ i_idx,
    const int* __restrict__ u_nbt, const int* __restrict__ i_nbt,
    const float* __restrict__ u_scr, const float* __restrict__ i_scr,
    const float* __restrict__ u_emb, const float* __restrict__ i_emb,
    unsigned short* __restrict__ xb, int b0)
{
    __shared__ unsigned short SL[112][136];   // 30.5 KB  (272B stride: 2-way banks)
    __shared__ unsigned short ET[64][136];    // 17.4 KB
    __shared__ int nb[KN];

    const int t    = threadIdx.x;
    const int side = blockIdx.y;
    const int b    = b0 + blockIdx.x;

    const int*   idxs = side ? i_idx : u_idx;
    const int*   nbt  = side ? i_nbt : u_nbt;
    const float* scr  = side ? i_scr : u_scr;
    const float* emb  = side ? i_emb : u_emb;

    const int center = idxs[b];
    if (t < KN) nb[t] = nbt[(size_t)center * KN + t];

    // zero K-pad strips j in [100,128) of both operands (7 b64 per row)
    const ushort4v z4 = {0, 0, 0, 0};
    for (int idx = t; idx < 112 * 7 + 64 * 7; idx += 256) {
        if (idx < 784) {
            int r = idx / 7, c = idx - r * 7;
            *(ushort4v*)&SL[r][100 + c * 4] = z4;
        } else {
            int i2 = idx - 784;
            int r = i2 / 7, c = i2 - r * 7;
            *(ushort4v*)&ET[r][100 + c * 4] = z4;
        }
    }
    __syncthreads();      // nb ready for gathers

    // gather S: 100 rows x 25 float4, cvt bf16, row-major into SL
    for (int idx = t; idx < KN * 25; idx += 256) {
        int k = idx / 25, q = idx - k * 25;
        float4 v = *(const float4*)(scr + (size_t)nb[k] * KN + q * 4);
        ushort4v o = { f2bf(v.x), f2bf(v.y), f2bf(v.z), f2bf(v.w) };
        *(ushort4v*)&SL[k][q * 4] = o;
    }
    // gather E with 4x4 in-register transpose: tile (j0,d4) covers
    // rows j0*4..+3, cols d4*4..+3;  writes Et[d4*4+c][j0*4..+3]
    for (int idx = t; idx < 25 * 16; idx += 256) {
        int d4 = idx / 25, j0 = idx - d4 * 25;
        float4 v0 = *(const float4*)(emb + (size_t)nb[j0 * 4 + 0] * DE + d4 * 4);
        float4 v1 = *(const float4*)(emb + (size_t)nb[j0 * 4 + 1] * DE + d4 * 4);
        float4 v2 = *(const float4*)(emb + (size_t)nb[j0 * 4 + 2] * DE + d4 * 4);
        float4 v3 = *(const float4*)(emb + (size_t)nb[j0 * 4 + 3] * DE + d4 * 4);
        ushort4v o0 = { f2bf(v0.x), f2bf(v1.x), f2bf(v2.x), f2bf(v3.x) };
        ushort4v o1 = { f2bf(v0.y), f2bf(v1.y), f2bf(v2.y), f2bf(v3.y) };
        ushort4v o2 = { f2bf(v0.z), f2bf(v1.z), f2bf(v2.z), f2bf(v3.z) };
        ushort4v o3 = { f2bf(v0.w), f2bf(v1.w), f2bf(v2.w), f2bf(v3.w) };
        *(ushort4v*)&ET[d4 * 4 + 0][j0 * 4] = o0;
        *(ushort4v*)&ET[d4 * 4 + 1][j0 * 4] = o1;
        *(ushort4v*)&ET[d4 * 4 + 2][j0 * 4] = o2;
        *(ushort4v*)&ET[d4 * 4 + 3][j0 * 4] = o3;
    }
    __syncthreads();

    // MFMA: wave w owns N-tile d = w*16..w*16+15; 7 M-tiles x 4 K-steps
    const int w  = t >> 6;
    const int l  = t & 63;
    const int cl = l & 15;
    const int rg = l >> 4;

    f32x4 acc[7];
    #pragma unroll
    for (int m = 0; m < 7; ++m) acc[m] = (f32x4){0.f, 0.f, 0.f, 0.f};

    #pragma unroll
    for (int ks = 0; ks < 4; ++ks) {
        const int kcol = ks * 32 + rg * 8;
        bf16x8 bfrag = *(const bf16x8*)&ET[w * 16 + cl][kcol];
        #pragma unroll
        for (int mt = 0; mt < 7; ++mt) {
            bf16x8 afrag = *(const bf16x8*)&SL[mt * 16 + cl][kcol];
            acc[mt] = __builtin_amdgcn_mfma_f32_16x16x32_bf16(afrag, bfrag, acc[mt], 0, 0, 0);
        }
    }
    __syncthreads();

    // bounce D through LDS (reuse SL space; row pad 72 -> 2-way banks)
    unsigned short* X = &SL[0][0];
    #pragma unroll
    for (int mt = 0; mt < 7; ++mt) {
        #pragma unroll
        for (int rr = 0; rr < 4; ++rr) {
            int k = mt * 16 + rg * 4 + rr;
            if (k < KN) X[k * 72 + w * 16 + cl] = f2bf(acc[mt][rr]);
        }
    }
    __syncthreads();

    // coalesced bf16 store: 100 rows x 8 b128 chunks
    unsigned short* xr = xb + (size_t)blockIdx.x * CAT + side * (KN * DE);
    for (int idx = t; idx < KN * 8; idx += 256) {
        int r = idx >> 3, c8 = idx & 7;
        *(ushort8v*)&xr[r * DE + c8 * 8] = *(const ushort8v*)&X[r * 72 + c8 * 8];
    }
}

// ---------------------------------------------------------------------------
// Kernel 2: bf16 MFMA MLP (unchanged from round 2; ~90us total).
// ---------------------------------------------------------------------------
__global__ __launch_bounds__(256) void mlp_kernel(
    const unsigned short* __restrict__ xb, const unsigned short* __restrict__ w1t,
    const float* __restrict__ b1, const float* __restrict__ W2,
    const float* __restrict__ b2, float* __restrict__ out, int b0)
{
    __shared__ unsigned short A[32][136];
    __shared__ unsigned short Bt[HID][136];
    __shared__ float red[4][32];

    const int t    = threadIdx.x;
    const int w    = t >> 6;
    const int l    = t & 63;
    const int cl   = l & 15;
    const int rgrp = l >> 4;
    const int row0 = blockIdx.x * 32;

    f32x4 acc[2][2];
    #pragma unroll
    for (int i = 0; i < 2; ++i)
        #pragma unroll
        for (int j = 0; j < 2; ++j)
            acc[i][j] = (f32x4){0.f, 0.f, 0.f, 0.f};

    for (int kb = 0; kb < CAT; kb += 128) {
        if (kb) __syncthreads();
        #pragma unroll
        for (int i = 0; i < 2; ++i) {
            int c = t + i * 256;
            int r = c >> 4, c16 = c & 15;
            *(ushort8v*)&A[r][c16 * 8] =
                *(const ushort8v*)&xb[(size_t)(row0 + r) * CAT + kb + c16 * 8];
        }
        #pragma unroll
        for (int i = 0; i < 8; ++i) {
            int c = t + i * 256;
            int n = c >> 4, c16 = c & 15;
            *(ushort8v*)&Bt[n][c16 * 8] =
                *(const ushort8v*)&w1t[(size_t)n * CAT + kb + c16 * 8];
        }
        __syncthreads();

        #pragma unroll
        for (int ks = 0; ks < 4; ++ks) {
            const int kcol = ks * 32 + rgrp * 8;
            bf16x8 a0 = *(const bf16x8*)&A[cl][kcol];
            bf16x8 a1 = *(const bf16x8*)&A[16 + cl][kcol];
            bf16x8 v0 = *(const bf16x8*)&Bt[w * 32 + cl][kcol];
            bf16x8 v1 = *(const bf16x8*)&Bt[w * 32 + 16 + cl][kcol];
            acc[0][0] = __builtin_amdgcn_mfma_f32_16x16x32_bf16(a0, v0, acc[0][0], 0, 0, 0);
            acc[0][1] = __builtin_amdgcn_mfma_f32_16x16x32_bf16(a0, v1, acc[0][1], 0, 0, 0);
            acc[1][0] = __builtin_amdgcn_mfma_f32_16x16x32_bf16(a1, v0, acc[1][0], 0, 0, 0);
            acc[1][1] = __builtin_amdgcn_mfma_f32_16x16x32_bf16(a1, v1, acc[1][1], 0, 0, 0);
        }
    }

    const float b1c0 = b1[w * 32 + cl];
    const float b1c1 = b1[w * 32 + 16 + cl];
    const float w2c0 = W2[w * 32 + cl];
    const float w2c1 = W2[w * 32 + 16 + cl];

    #pragma unroll
    for (int mt = 0; mt < 2; ++mt) {
        #pragma unroll
        for (int r = 0; r < 4; ++r) {
            float h0 = fmaxf(acc[mt][0][r] + b1c0, 0.f);
            float h1 = fmaxf(acc[mt][1][r] + b1c1, 0.f);
            float p  = fmaf(h0, w2c0, h1 * w2c1);
            p += __shfl_xor(p, 1, 64);
            p += __shfl_xor(p, 2, 64);
            p += __shfl_xor(p, 4, 64);
            p += __shfl_xor(p, 8, 64);
            if (cl == 0) red[w][mt * 16 + rgrp * 4 + r] = p;
        }
    }
    __syncthreads();
    if (t < 32) {
        float o = red[0][t] + red[1][t] + red[2][t] + red[3][t] + b2[0];
        o = fmaxf(o, 0.f);
        out[b0 + row0 + t] = 1.f / (1.f + expf(-o));
    }
}

// ---------------------------------------------------------------------------
extern "C" void kernel_launch(void* const* d_in, const int* in_sizes, int n_in,
                              void* d_out, int out_size, void* d_ws, size_t ws_size,
                              hipStream_t stream)
{
    const int*   user_idxs = (const int*)d_in[0];
    const int*   item_idxs = (const int*)d_in[1];
    const int*   user_nbt  = (const int*)d_in[2];
    const int*   item_nbt  = (const int*)d_in[3];
    const float* user_scr  = (const float*)d_in[4];
    const float* item_scr  = (const float*)d_in[5];
    const float* user_emb  = (const float*)d_in[6];
    const float* item_emb  = (const float*)d_in[7];
    const float* W1        = (const float*)d_in[8];
    const float* b1        = (const float*)d_in[9];
    const float* W2        = (const float*)d_in[10];
    const float* b2        = (const float*)d_in[11];
    float*       out       = (float*)d_out;

    const int B = in_sizes[0];      // 8192

    const size_t w1t_bytes = (size_t)HID * CAT * sizeof(unsigned short); // 3.3 MB
    unsigned short* w1t = (unsigned short*)d_ws;
    unsigned short* xb  = (unsigned short*)((char*)d_ws + w1t_bytes);

    const size_t row_bytes = (size_t)CAT * sizeof(unsigned short);
    long max_rows = (long)((ws_size - w1t_bytes) / row_bytes);
    int chunk = (int)((max_rows / 32) * 32);
    if (chunk > B) chunk = B;
    if (chunk < 32) chunk = 32;

    prep_w1t<<<CAT / 64, 256, 0, stream>>>(W1, w1t);

    for (int b0 = 0; b0 < B; b0 += chunk) {
        int rows = (B - b0 < chunk) ? (B - b0) : chunk;
        einsum_mfma<<<dim3(rows, 2), 256, 0, stream>>>(
            user_idxs, item_idxs, user_nbt, item_nbt,
            user_scr, item_scr, user_emb, item_emb, xb, b0);
        mlp_kernel<<<rows / 32, 256, 0, stream>>>(
            xb, w1t, b1, W2, b2, out, b0);
    }
}

// Round 4
// 363.729 us; speedup vs baseline: 6.5990x; 1.0142x over previous
//
#include <hip/hip_runtime.h>
#include <hip/hip_bf16.h>
#include <math.h>

constexpr int KN  = 100;            // K (multi_factor * top_k)
constexpr int DE  = 64;             // embedding dim
constexpr int CAT = 2 * KN * DE;    // 12800
constexpr int HID = 128;

typedef __bf16          bf16x8   __attribute__((ext_vector_type(8)));
typedef float           f32x4    __attribute__((ext_vector_type(4)));
typedef unsigned short  ushort8v __attribute__((ext_vector_type(8)));
typedef unsigned short  ushort4v __attribute__((ext_vector_type(4)));

static __device__ __forceinline__ unsigned short f2bf(float f) {
    __hip_bfloat16 h = __float2bfloat16(f);
    return *reinterpret_cast<unsigned short*>(&h);
}

// ---------------------------------------------------------------------------
// prep: elementwise fp32 -> bf16 table conversion (grid-stride, float4 in,
// ushort4 out).  Hoists the per-gather cvt out of the einsum and halves the
// gathered bytes.
// ---------------------------------------------------------------------------
__global__ __launch_bounds__(256) void cvt_bf16(
    const float* __restrict__ in, unsigned short* __restrict__ out, int n4)
{
    int i = blockIdx.x * blockDim.x + threadIdx.x;
    const int stride = gridDim.x * blockDim.x;
    for (; i < n4; i += stride) {
        float4 v = ((const float4*)in)[i];
        ushort4v o = { f2bf(v.x), f2bf(v.y), f2bf(v.z), f2bf(v.w) };
        ((ushort4v*)out)[i] = o;
    }
}

// ---------------------------------------------------------------------------
// prep: w1t[n][k] = bf16(W1[k][n]) (unchanged, known-good)
// ---------------------------------------------------------------------------
__global__ __launch_bounds__(256) void prep_w1t(
    const float* __restrict__ W1, unsigned short* __restrict__ w1t)
{
    __shared__ unsigned short T[HID][72];
    const int t  = threadIdx.x;
    const int k0 = blockIdx.x * 64;

    for (int idx = t; idx < 64 * HID; idx += 256) {
        int kk = idx >> 7, n = idx & 127;
        T[n][kk] = f2bf(W1[(size_t)(k0 + kk) * HID + n]);
    }
    __syncthreads();
    for (int idx = t; idx < HID * 16; idx += 256) {
        int n = idx >> 4, c4 = idx & 15;
        *(ushort4v*)&w1t[(size_t)n * CAT + k0 + c4 * 4] =
            *(const ushort4v*)&T[n][c4 * 4];
    }
}

// ---------------------------------------------------------------------------
// Kernel 1 (MFMA, bf16 tables): per (batch row, side) block, scored = S @ E.
// S staged one K-half at a time (SL[112][72], 2 phases) to cut LDS to 33.9KB
// -> 4 blocks/CU.  ET[64][136] full-K (E transposed in-register at gather).
// K-pad strips zeroed on both operands (NaN*0 hazard).  Output bounced
// through SL for coalesced b128 stores.
// ---------------------------------------------------------------------------
__global__ __launch_bounds__(256) void einsum_mfma(
    const int* __restrict__ u_idx, const int* __restrict__ i_idx,
    const int* __restrict__ u_nbt, const int* __restrict__ i_nbt,
    const unsigned short* __restrict__ u_scr, const unsigned short* __restrict__ i_scr,
    const unsigned short* __restrict__ u_emb, const unsigned short* __restrict__ i_emb,
    unsigned short* __restrict__ xb, int b0)
{
    __shared__ unsigned short SL[112][72];    // 16.1 KB  (one 64-col K-half + 8 pad)
    __shared__ unsigned short ET[64][136];    // 17.4 KB  (full K=128 + 8 pad)
    __shared__ int nb[KN];

    const int t    = threadIdx.x;
    const int side = blockIdx.y;
    const int b    = b0 + blockIdx.x;

    const int*            idxs = side ? i_idx : u_idx;
    const int*            nbt  = side ? i_nbt : u_nbt;
    const unsigned short* scr  = side ? i_scr : u_scr;
    const unsigned short* emb  = side ? i_emb : u_emb;

    const ushort4v z4 = {0, 0, 0, 0};

    const int center = idxs[b];
    if (t < KN) nb[t] = nbt[(size_t)center * KN + t];

    // zero ET K-pad strip j in [100,128)
    for (int idx = t; idx < 64 * 7; idx += 256) {
        int r = idx / 7, c = idx - r * 7;
        *(ushort4v*)&ET[r][100 + c * 4] = z4;
    }
    __syncthreads();                           // nb ready

    // gather E with 4x4 u16 transpose: tile (j0,d4) -> ET[d4*4+c][j0*4..+3]
    for (int idx = t; idx < 25 * 16; idx += 256) {
        int d4 = idx / 25, j0 = idx - d4 * 25;
        ushort4v v0 = *(const ushort4v*)(emb + (size_t)nb[j0 * 4 + 0] * DE + d4 * 4);
        ushort4v v1 = *(const ushort4v*)(emb + (size_t)nb[j0 * 4 + 1] * DE + d4 * 4);
        ushort4v v2 = *(const ushort4v*)(emb + (size_t)nb[j0 * 4 + 2] * DE + d4 * 4);
        ushort4v v3 = *(const ushort4v*)(emb + (size_t)nb[j0 * 4 + 3] * DE + d4 * 4);
        ushort4v o0 = { v0[0], v1[0], v2[0], v3[0] };
        ushort4v o1 = { v0[1], v1[1], v2[1], v3[1] };
        ushort4v o2 = { v0[2], v1[2], v2[2], v3[2] };
        ushort4v o3 = { v0[3], v1[3], v2[3], v3[3] };
        *(ushort4v*)&ET[d4 * 4 + 0][j0 * 4] = o0;
        *(ushort4v*)&ET[d4 * 4 + 1][j0 * 4] = o1;
        *(ushort4v*)&ET[d4 * 4 + 2][j0 * 4] = o2;
        *(ushort4v*)&ET[d4 * 4 + 3][j0 * 4] = o3;
    }
    // gather S K-half 0: cols j = 0..63
    for (int idx = t; idx < KN * 16; idx += 256) {
        int k = idx >> 4, q = idx & 15;
        *(ushort4v*)&SL[k][q * 4] =
            *(const ushort4v*)(scr + (size_t)nb[k] * KN + q * 4);
    }
    __syncthreads();

    const int w  = t >> 6;
    const int l  = t & 63;
    const int cl = l & 15;
    const int rg = l >> 4;

    f32x4 acc[7];
    #pragma unroll
    for (int m = 0; m < 7; ++m) acc[m] = (f32x4){0.f, 0.f, 0.f, 0.f};

    // MFMA K-half 0 (ks 0,1)
    #pragma unroll
    for (int ks = 0; ks < 2; ++ks) {
        const int kcol = ks * 32 + rg * 8;
        bf16x8 bfrag = *(const bf16x8*)&ET[w * 16 + cl][kcol];
        #pragma unroll
        for (int mt = 0; mt < 7; ++mt) {
            bf16x8 afrag = *(const bf16x8*)&SL[mt * 16 + cl][kcol];
            acc[mt] = __builtin_amdgcn_mfma_f32_16x16x32_bf16(afrag, bfrag, acc[mt], 0, 0, 0);
        }
    }
    __syncthreads();                           // SL reads done

    // gather S K-half 1: cols j = 64..99, zero j = 100..127
    for (int idx = t; idx < KN * 16; idx += 256) {
        int k = idx >> 4, q = idx & 15;
        ushort4v v = (q < 9)
            ? *(const ushort4v*)(scr + (size_t)nb[k] * KN + 64 + q * 4) : z4;
        *(ushort4v*)&SL[k][q * 4] = v;
    }
    __syncthreads();

    // MFMA K-half 1 (ks 2,3)
    #pragma unroll
    for (int ks = 0; ks < 2; ++ks) {
        const int kcol = ks * 32 + rg * 8;
        bf16x8 bfrag = *(const bf16x8*)&ET[w * 16 + cl][64 + kcol];
        #pragma unroll
        for (int mt = 0; mt < 7; ++mt) {
            bf16x8 afrag = *(const bf16x8*)&SL[mt * 16 + cl][kcol];
            acc[mt] = __builtin_amdgcn_mfma_f32_16x16x32_bf16(afrag, bfrag, acc[mt], 0, 0, 0);
        }
    }
    __syncthreads();

    // bounce D through SL (stride 72) for coalesced stores
    unsigned short* X = &SL[0][0];
    #pragma unroll
    for (int mt = 0; mt < 7; ++mt) {
        #pragma unroll
        for (int rr = 0; rr < 4; ++rr) {
            int k = mt * 16 + rg * 4 + rr;
            if (k < KN) X[k * 72 + w * 16 + cl] = f2bf(acc[mt][rr]);
        }
    }
    __syncthreads();

    unsigned short* xr = xb + (size_t)blockIdx.x * CAT + side * (KN * DE);
    for (int idx = t; idx < KN * 8; idx += 256) {
        int r = idx >> 3, c8 = idx & 7;
        *(ushort8v*)&xr[r * DE + c8 * 8] = *(const ushort8v*)&X[r * 72 + c8 * 8];
    }
}

// ---------------------------------------------------------------------------
// Kernel 2: bf16 MFMA MLP (unchanged, known-good)
// ---------------------------------------------------------------------------
__global__ __launch_bounds__(256) void mlp_kernel(
    const unsigned short* __restrict__ xb, const unsigned short* __restrict__ w1t,
    const float* __restrict__ b1, const float* __restrict__ W2,
    const float* __restrict__ b2, float* __restrict__ out, int b0)
{
    __shared__ unsigned short A[32][136];
    __shared__ unsigned short Bt[HID][136];
    __shared__ float red[4][32];

    const int t    = threadIdx.x;
    const int w    = t >> 6;
    const int l    = t & 63;
    const int cl   = l & 15;
    const int rgrp = l >> 4;
    const int row0 = blockIdx.x * 32;

    f32x4 acc[2][2];
    #pragma unroll
    for (int i = 0; i < 2; ++i)
        #pragma unroll
        for (int j = 0; j < 2; ++j)
            acc[i][j] = (f32x4){0.f, 0.f, 0.f, 0.f};

    for (int kb = 0; kb < CAT; kb += 128) {
        if (kb) __syncthreads();
        #pragma unroll
        for (int i = 0; i < 2; ++i) {
            int c = t + i * 256;
            int r = c >> 4, c16 = c & 15;
            *(ushort8v*)&A[r][c16 * 8] =
                *(const ushort8v*)&xb[(size_t)(row0 + r) * CAT + kb + c16 * 8];
        }
        #pragma unroll
        for (int i = 0; i < 8; ++i) {
            int c = t + i * 256;
            int n = c >> 4, c16 = c & 15;
            *(ushort8v*)&Bt[n][c16 * 8] =
                *(const ushort8v*)&w1t[(size_t)n * CAT + kb + c16 * 8];
        }
        __syncthreads();

        #pragma unroll
        for (int ks = 0; ks < 4; ++ks) {
            const int kcol = ks * 32 + rgrp * 8;
            bf16x8 a0 = *(const bf16x8*)&A[cl][kcol];
            bf16x8 a1 = *(const bf16x8*)&A[16 + cl][kcol];
            bf16x8 v0 = *(const bf16x8*)&Bt[w * 32 + cl][kcol];
            bf16x8 v1 = *(const bf16x8*)&Bt[w * 32 + 16 + cl][kcol];
            acc[0][0] = __builtin_amdgcn_mfma_f32_16x16x32_bf16(a0, v0, acc[0][0], 0, 0, 0);
            acc[0][1] = __builtin_amdgcn_mfma_f32_16x16x32_bf16(a0, v1, acc[0][1], 0, 0, 0);
            acc[1][0] = __builtin_amdgcn_mfma_f32_16x16x32_bf16(a1, v0, acc[1][0], 0, 0, 0);
            acc[1][1] = __builtin_amdgcn_mfma_f32_16x16x32_bf16(a1, v1, acc[1][1], 0, 0, 0);
        }
    }

    const float b1c0 = b1[w * 32 + cl];
    const float b1c1 = b1[w * 32 + 16 + cl];
    const float w2c0 = W2[w * 32 + cl];
    const float w2c1 = W2[w * 32 + 16 + cl];

    #pragma unroll
    for (int mt = 0; mt < 2; ++mt) {
        #pragma unroll
        for (int r = 0; r < 4; ++r) {
            float h0 = fmaxf(acc[mt][0][r] + b1c0, 0.f);
            float h1 = fmaxf(acc[mt][1][r] + b1c1, 0.f);
            float p  = fmaf(h0, w2c0, h1 * w2c1);
            p += __shfl_xor(p, 1, 64);
            p += __shfl_xor(p, 2, 64);
            p += __shfl_xor(p, 4, 64);
            p += __shfl_xor(p, 8, 64);
            if (cl == 0) red[w][mt * 16 + rgrp * 4 + r] = p;
        }
    }
    __syncthreads();
    if (t < 32) {
        float o = red[0][t] + red[1][t] + red[2][t] + red[3][t] + b2[0];
        o = fmaxf(o, 0.f);
        out[b0 + row0 + t] = 1.f / (1.f + expf(-o));
    }
}

// ---------------------------------------------------------------------------
extern "C" void kernel_launch(void* const* d_in, const int* in_sizes, int n_in,
                              void* d_out, int out_size, void* d_ws, size_t ws_size,
                              hipStream_t stream)
{
    const int*   user_idxs = (const int*)d_in[0];
    const int*   item_idxs = (const int*)d_in[1];
    const int*   user_nbt  = (const int*)d_in[2];
    const int*   item_nbt  = (const int*)d_in[3];
    const float* user_scr  = (const float*)d_in[4];
    const float* item_scr  = (const float*)d_in[5];
    const float* user_emb  = (const float*)d_in[6];
    const float* item_emb  = (const float*)d_in[7];
    const float* W1        = (const float*)d_in[8];
    const float* b1        = (const float*)d_in[9];
    const float* W2        = (const float*)d_in[10];
    const float* b2        = (const float*)d_in[11];
    float*       out       = (float*)d_out;

    const int B = in_sizes[0];      // 8192

    // ws layout: [w1t][us_bf][is_bf][ue_bf][ie_bf][xb]
    char* p = (char*)d_ws;
    unsigned short* w1t   = (unsigned short*)p;  p += (size_t)HID * CAT * 2;
    unsigned short* us_bf = (unsigned short*)p;  p += (size_t)in_sizes[4] * 2;
    unsigned short* is_bf = (unsigned short*)p;  p += (size_t)in_sizes[5] * 2;
    unsigned short* ue_bf = (unsigned short*)p;  p += (size_t)in_sizes[6] * 2;
    unsigned short* ie_bf = (unsigned short*)p;  p += (size_t)in_sizes[7] * 2;
    unsigned short* xb    = (unsigned short*)p;
    const size_t fixed = (size_t)(p - (char*)d_ws);

    const size_t row_bytes = (size_t)CAT * sizeof(unsigned short);
    long max_rows = (long)((ws_size - fixed) / row_bytes);
    int chunk = (int)((max_rows / 32) * 32);
    if (chunk > B) chunk = B;
    if (chunk < 32) chunk = 32;

    prep_w1t<<<CAT / 64, 256, 0, stream>>>(W1, w1t);
    cvt_bf16<<<2048, 256, 0, stream>>>(user_scr, us_bf, in_sizes[4] / 4);
    cvt_bf16<<<2048, 256, 0, stream>>>(item_scr, is_bf, in_sizes[5] / 4);
    cvt_bf16<<<2048, 256, 0, stream>>>(user_emb, ue_bf, in_sizes[6] / 4);
    cvt_bf16<<<2048, 256, 0, stream>>>(item_emb, ie_bf, in_sizes[7] / 4);

    for (int b0 = 0; b0 < B; b0 += chunk) {
        int rows = (B - b0 < chunk) ? (B - b0) : chunk;
        einsum_mfma<<<dim3(rows, 2), 256, 0, stream>>>(
            user_idxs, item_idxs, user_nbt, item_nbt,
            us_bf, is_bf, ue_bf, ie_bf, xb, b0);
        mlp_kernel<<<rows / 32, 256, 0, stream>>>(
            xb, w1t, b1, W2, b2, out, b0);
    }
}

// Round 6
// 344.853 us; speedup vs baseline: 6.9602x; 1.0547x over previous
//
#include <hip/hip_runtime.h>
#include <hip/hip_bf16.h>
#include <math.h>

constexpr int KN  = 100;            // K (multi_factor * top_k)
constexpr int DE  = 64;             // embedding dim
constexpr int CAT = 2 * KN * DE;    // 12800
constexpr int HID = 128;

typedef __bf16          bf16x8   __attribute__((ext_vector_type(8)));
typedef float           f32x4    __attribute__((ext_vector_type(4)));
typedef unsigned short  ushort8v __attribute__((ext_vector_type(8)));
typedef unsigned short  ushort4v __attribute__((ext_vector_type(4)));

static __device__ __forceinline__ unsigned short f2bf(float f) {
    __hip_bfloat16 h = __float2bfloat16(f);
    return *reinterpret_cast<unsigned short*>(&h);
}

static __device__ __forceinline__ bf16x8 mk_frag(ushort4v lo, ushort4v hi) {
    union { ushort8v u; bf16x8 b; } c;
    c.u = (ushort8v){ lo[0], lo[1], lo[2], lo[3], hi[0], hi[1], hi[2], hi[3] };
    return c.b;
}

// ---------------------------------------------------------------------------
// prep: 4 fp32->bf16 table conversions in one launch (blockIdx.y = segment)
// ---------------------------------------------------------------------------
__global__ __launch_bounds__(256) void cvt4(
    const float* __restrict__ a0, unsigned short* __restrict__ o0, int n0,
    const float* __restrict__ a1, unsigned short* __restrict__ o1, int n1,
    const float* __restrict__ a2, unsigned short* __restrict__ o2, int n2,
    const float* __restrict__ a3, unsigned short* __restrict__ o3, int n3)
{
    const float* in; unsigned short* out; int n4;
    switch (blockIdx.y) {
        case 0:  in = a0; out = o0; n4 = n0; break;
        case 1:  in = a1; out = o1; n4 = n1; break;
        case 2:  in = a2; out = o2; n4 = n2; break;
        default: in = a3; out = o3; n4 = n3; break;
    }
    for (int i = blockIdx.x * 256 + threadIdx.x; i < n4; i += gridDim.x * 256) {
        float4 v = ((const float4*)in)[i];
        ushort4v o = { f2bf(v.x), f2bf(v.y), f2bf(v.z), f2bf(v.w) };
        ((ushort4v*)out)[i] = o;
    }
}

// ---------------------------------------------------------------------------
// prep: w1t[n][k] = bf16(W1[k][n]) (unchanged, known-good)
// ---------------------------------------------------------------------------
__global__ __launch_bounds__(256) void prep_w1t(
    const float* __restrict__ W1, unsigned short* __restrict__ w1t)
{
    __shared__ unsigned short T[HID][72];
    const int t  = threadIdx.x;
    const int k0 = blockIdx.x * 64;

    for (int idx = t; idx < 64 * HID; idx += 256) {
        int kk = idx >> 7, n = idx & 127;
        T[n][kk] = f2bf(W1[(size_t)(k0 + kk) * HID + n]);
    }
    __syncthreads();
    for (int idx = t; idx < HID * 16; idx += 256) {
        int n = idx >> 4, c4 = idx & 15;
        *(ushort4v*)&w1t[(size_t)n * CAT + k0 + c4 * 4] =
            *(const ushort4v*)&T[n][c4 * 4];
    }
}

// ---------------------------------------------------------------------------
// Kernel 1 v5b: S fragments loaded DIRECTLY global->register (A-layout is 8
// k-contiguous bf16 per lane = two 8B loads; rows 8B-aligned).  Row index
// mt*16+cl CLAMPED to KN-1 (v5 crash: rows 100..111 read nb[] OOB and used
// garbage as a gather index).  Only E is LDS-staged.  K-tail via masked ks=3
// loads AND zeroed ET pad.  xb stored nontemporal.
// ---------------------------------------------------------------------------
__global__ __launch_bounds__(256) void einsum_mfma(
    const int* __restrict__ u_idx, const int* __restrict__ i_idx,
    const int* __restrict__ u_nbt, const int* __restrict__ i_nbt,
    const unsigned short* __restrict__ u_scr, const unsigned short* __restrict__ i_scr,
    const unsigned short* __restrict__ u_emb, const unsigned short* __restrict__ i_emb,
    unsigned short* __restrict__ xb, int b0)
{
    __shared__ __align__(16) unsigned short ET[64][136];  // 17.4 KB; reused as D-bounce
    __shared__ int nb[KN];

    const int t    = threadIdx.x;
    const int side = blockIdx.y;
    const int b    = b0 + blockIdx.x;

    const int*            idxs = side ? i_idx : u_idx;
    const int*            nbt  = side ? i_nbt : u_nbt;
    const unsigned short* scr  = side ? i_scr : u_scr;
    const unsigned short* emb  = side ? i_emb : u_emb;

    const ushort4v z4 = {0, 0, 0, 0};

    const int center = idxs[b];
    if (t < KN) nb[t] = nbt[(size_t)center * KN + t];

    // zero ET K-pad strip j in [100,128)
    for (int idx = t; idx < 64 * 7; idx += 256) {
        int r = idx / 7, c = idx - r * 7;
        *(ushort4v*)&ET[r][100 + c * 4] = z4;
    }
    __syncthreads();                           // nb ready

    // gather E with 4x4 u16 transpose: tile (j0,d4) -> ET[d4*4+c][j0*4..+3]
    for (int idx = t; idx < 25 * 16; idx += 256) {
        int d4 = idx / 25, j0 = idx - d4 * 25;
        ushort4v v0 = *(const ushort4v*)(emb + (size_t)nb[j0 * 4 + 0] * DE + d4 * 4);
        ushort4v v1 = *(const ushort4v*)(emb + (size_t)nb[j0 * 4 + 1] * DE + d4 * 4);
        ushort4v v2 = *(const ushort4v*)(emb + (size_t)nb[j0 * 4 + 2] * DE + d4 * 4);
        ushort4v v3 = *(const ushort4v*)(emb + (size_t)nb[j0 * 4 + 3] * DE + d4 * 4);
        ushort4v o0 = { v0[0], v1[0], v2[0], v3[0] };
        ushort4v o1 = { v0[1], v1[1], v2[1], v3[1] };
        ushort4v o2 = { v0[2], v1[2], v2[2], v3[2] };
        ushort4v o3 = { v0[3], v1[3], v2[3], v3[3] };
        *(ushort4v*)&ET[d4 * 4 + 0][j0 * 4] = o0;
        *(ushort4v*)&ET[d4 * 4 + 1][j0 * 4] = o1;
        *(ushort4v*)&ET[d4 * 4 + 2][j0 * 4] = o2;
        *(ushort4v*)&ET[d4 * 4 + 3][j0 * 4] = o3;
    }
    __syncthreads();

    const int w  = t >> 6;
    const int l  = t & 63;
    const int cl = l & 15;
    const int rg = l >> 4;

    // per-lane S row bases (A-fragment rows), CLAMPED to valid range.
    // Lanes mapping to k in [100,112) gather row 99 redundantly; their
    // accumulator rows are never stored (k < KN guard at the bounce).
    const unsigned short* srow[7];
    #pragma unroll
    for (int mt = 0; mt < 7; ++mt) {
        int kr = mt * 16 + cl;
        if (kr > KN - 1) kr = KN - 1;
        srow[mt] = scr + (size_t)nb[kr] * KN;
    }

    f32x4 acc[7];
    #pragma unroll
    for (int m = 0; m < 7; ++m) acc[m] = (f32x4){0.f, 0.f, 0.f, 0.f};

    #pragma unroll
    for (int ks = 0; ks < 4; ++ks) {
        const int k0 = ks * 32 + rg * 8;
        bf16x8 bfrag = *(const bf16x8*)&ET[w * 16 + cl][k0];
        #pragma unroll
        for (int mt = 0; mt < 7; ++mt) {
            ushort4v lo, hi;
            if (ks < 3) {                        // k0 in [0,88]: fully valid
                lo = *(const ushort4v*)(srow[mt] + k0);
                hi = *(const ushort4v*)(srow[mt] + k0 + 4);
            } else if (rg == 0) {                // k 96..99 valid, 100..103 zero
                lo = *(const ushort4v*)(srow[mt] + 96);
                hi = z4;
            } else {                             // k >= 104: all pad
                lo = z4; hi = z4;
            }
            bf16x8 afrag = mk_frag(lo, hi);
            acc[mt] = __builtin_amdgcn_mfma_f32_16x16x32_bf16(afrag, bfrag, acc[mt], 0, 0, 0);
        }
    }
    __syncthreads();                             // all ET reads done

    // bounce D through LDS (alias over ET; stride 72 ushorts)
    unsigned short* X = &ET[0][0];
    #pragma unroll
    for (int mt = 0; mt < 7; ++mt) {
        #pragma unroll
        for (int rr = 0; rr < 4; ++rr) {
            int k = mt * 16 + rg * 4 + rr;
            if (k < KN) X[k * 72 + w * 16 + cl] = f2bf(acc[mt][rr]);
        }
    }
    __syncthreads();

    // coalesced NONTEMPORAL store (don't evict gather tables from L2/L3)
    unsigned short* xr = xb + (size_t)blockIdx.x * CAT + side * (KN * DE);
    for (int idx = t; idx < KN * 8; idx += 256) {
        int r = idx >> 3, c8 = idx & 7;
        __builtin_nontemporal_store(*(const ushort8v*)&X[r * 72 + c8 * 8],
                                    (ushort8v*)&xr[r * DE + c8 * 8]);
    }
}

// ---------------------------------------------------------------------------
// Kernel 2: bf16 MFMA MLP.  xb read nontemporal (stream-once; keep w1t hot).
// ---------------------------------------------------------------------------
__global__ __launch_bounds__(256) void mlp_kernel(
    const unsigned short* __restrict__ xb, const unsigned short* __restrict__ w1t,
    const float* __restrict__ b1, const float* __restrict__ W2,
    const float* __restrict__ b2, float* __restrict__ out, int b0)
{
    __shared__ unsigned short A[32][136];
    __shared__ unsigned short Bt[HID][136];
    __shared__ float red[4][32];

    const int t    = threadIdx.x;
    const int w    = t >> 6;
    const int l    = t & 63;
    const int cl   = l & 15;
    const int rgrp = l >> 4;
    const int row0 = blockIdx.x * 32;

    f32x4 acc[2][2];
    #pragma unroll
    for (int i = 0; i < 2; ++i)
        #pragma unroll
        for (int j = 0; j < 2; ++j)
            acc[i][j] = (f32x4){0.f, 0.f, 0.f, 0.f};

    for (int kb = 0; kb < CAT; kb += 128) {
        if (kb) __syncthreads();
        #pragma unroll
        for (int i = 0; i < 2; ++i) {
            int c = t + i * 256;
            int r = c >> 4, c16 = c & 15;
            *(ushort8v*)&A[r][c16 * 8] = __builtin_nontemporal_load(
                (const ushort8v*)&xb[(size_t)(row0 + r) * CAT + kb + c16 * 8]);
        }
        #pragma unroll
        for (int i = 0; i < 8; ++i) {
            int c = t + i * 256;
            int n = c >> 4, c16 = c & 15;
            *(ushort8v*)&Bt[n][c16 * 8] =
                *(const ushort8v*)&w1t[(size_t)n * CAT + kb + c16 * 8];
        }
        __syncthreads();

        #pragma unroll
        for (int ks = 0; ks < 4; ++ks) {
            const int kcol = ks * 32 + rgrp * 8;
            bf16x8 a0 = *(const bf16x8*)&A[cl][kcol];
            bf16x8 a1 = *(const bf16x8*)&A[16 + cl][kcol];
            bf16x8 v0 = *(const bf16x8*)&Bt[w * 32 + cl][kcol];
            bf16x8 v1 = *(const bf16x8*)&Bt[w * 32 + 16 + cl][kcol];
            acc[0][0] = __builtin_amdgcn_mfma_f32_16x16x32_bf16(a0, v0, acc[0][0], 0, 0, 0);
            acc[0][1] = __builtin_amdgcn_mfma_f32_16x16x32_bf16(a0, v1, acc[0][1], 0, 0, 0);
            acc[1][0] = __builtin_amdgcn_mfma_f32_16x16x32_bf16(a1, v0, acc[1][0], 0, 0, 0);
            acc[1][1] = __builtin_amdgcn_mfma_f32_16x16x32_bf16(a1, v1, acc[1][1], 0, 0, 0);
        }
    }

    const float b1c0 = b1[w * 32 + cl];
    const float b1c1 = b1[w * 32 + 16 + cl];
    const float w2c0 = W2[w * 32 + cl];
    const float w2c1 = W2[w * 32 + 16 + cl];

    #pragma unroll
    for (int mt = 0; mt < 2; ++mt) {
        #pragma unroll
        for (int r = 0; r < 4; ++r) {
            float h0 = fmaxf(acc[mt][0][r] + b1c0, 0.f);
            float h1 = fmaxf(acc[mt][1][r] + b1c1, 0.f);
            float p  = fmaf(h0, w2c0, h1 * w2c1);
            p += __shfl_xor(p, 1, 64);
            p += __shfl_xor(p, 2, 64);
            p += __shfl_xor(p, 4, 64);
            p += __shfl_xor(p, 8, 64);
            if (cl == 0) red[w][mt * 16 + rgrp * 4 + r] = p;
        }
    }
    __syncthreads();
    if (t < 32) {
        float o = red[0][t] + red[1][t] + red[2][t] + red[3][t] + b2[0];
        o = fmaxf(o, 0.f);
        out[b0 + row0 + t] = 1.f / (1.f + expf(-o));
    }
}

// ---------------------------------------------------------------------------
extern "C" void kernel_launch(void* const* d_in, const int* in_sizes, int n_in,
                              void* d_out, int out_size, void* d_ws, size_t ws_size,
                              hipStream_t stream)
{
    const int*   user_idxs = (const int*)d_in[0];
    const int*   item_idxs = (const int*)d_in[1];
    const int*   user_nbt  = (const int*)d_in[2];
    const int*   item_nbt  = (const int*)d_in[3];
    const float* user_scr  = (const float*)d_in[4];
    const float* item_scr  = (const float*)d_in[5];
    const float* user_emb  = (const float*)d_in[6];
    const float* item_emb  = (const float*)d_in[7];
    const float* W1        = (const float*)d_in[8];
    const float* b1        = (const float*)d_in[9];
    const float* W2        = (const float*)d_in[10];
    const float* b2        = (const float*)d_in[11];
    float*       out       = (float*)d_out;

    const int B = in_sizes[0];      // 8192

    // ws layout: [w1t][us_bf][is_bf][ue_bf][ie_bf][xb]
    char* p = (char*)d_ws;
    unsigned short* w1t   = (unsigned short*)p;  p += (size_t)HID * CAT * 2;
    unsigned short* us_bf = (unsigned short*)p;  p += (size_t)in_sizes[4] * 2;
    unsigned short* is_bf = (unsigned short*)p;  p += (size_t)in_sizes[5] * 2;
    unsigned short* ue_bf = (unsigned short*)p;  p += (size_t)in_sizes[6] * 2;
    unsigned short* ie_bf = (unsigned short*)p;  p += (size_t)in_sizes[7] * 2;
    unsigned short* xb    = (unsigned short*)p;
    const size_t fixed = (size_t)(p - (char*)d_ws);

    const size_t row_bytes = (size_t)CAT * sizeof(unsigned short);
    long max_rows = (long)((ws_size - fixed) / row_bytes);
    int chunk = (int)((max_rows / 32) * 32);
    if (chunk > B) chunk = B;
    if (chunk < 32) chunk = 32;

    prep_w1t<<<CAT / 64, 256, 0, stream>>>(W1, w1t);
    cvt4<<<dim3(512, 4), 256, 0, stream>>>(
        user_scr, us_bf, in_sizes[4] / 4,
        item_scr, is_bf, in_sizes[5] / 4,
        user_emb, ue_bf, in_sizes[6] / 4,
        item_emb, ie_bf, in_sizes[7] / 4);

    for (int b0 = 0; b0 < B; b0 += chunk) {
        int rows = (B - b0 < chunk) ? (B - b0) : chunk;
        einsum_mfma<<<dim3(rows, 2), 256, 0, stream>>>(
            user_idxs, item_idxs, user_nbt, item_nbt,
            us_bf, is_bf, ue_bf, ie_bf, xb, b0);
        mlp_kernel<<<rows / 32, 256, 0, stream>>>(
            xb, w1t, b1, W2, b2, out, b0);
    }
}